// Round 5
// baseline (183.789 us; speedup 1.0000x reference)
//
#include <hip/hip_runtime.h>

#define NUM_REGIONS 116
#define EPS 1e-6f
#define GAMMA 1e-3f

// u32 LDS packing: count in bits [21,32) (cap 2047), sum in bits [0,21) at
// 2^-11 fixed point (cap 1024.0). Per 8-lane sub-table: <=192 elements over
// 116 bins -> per-bin count ~2 max ~8; per-bin sum max ~12. Huge margin.
#define SUM_SCALE 2048.0f
#define CNT32_SHIFT 21
#define SUM32_MASK ((1u << CNT32_SHIFT) - 1u)

// u64 global packing: count in [40,64), sum (2^-11 units) in [0,40).
// Totals: count 12.6M < 2^24; sum 12.6M*1.13*2048 = 2.9e10 < 2^40.
#define FIX_INV   (1.0f / 2048.0f)
#define CNT_SHIFT 40
#define SUM_MASK  ((1ULL << CNT_SHIFT) - 1ULL)

// 8 sub-tables per wave (lane & 7) x 4 waves = 32 tables.
// Goal: cut same-address atomic chain serialization (8 lanes over 116 bins
// -> chains almost always length 1, vs length ~4-5 with 64 lanes/table).
#define NTBL 32

typedef unsigned long long u64;
typedef unsigned int u32;

__global__ __launch_bounds__(256) void region_accum_kernel(
    const float* __restrict__ real,
    const float* __restrict__ fake,
    const int*   __restrict__ rmap,
    u64* __restrict__ g_acc,
    int n, int n4)
{
    __shared__ u32 s_acc[NTBL][NUM_REGIONS];
    const int tid = threadIdx.x;
    // wave id (tid>>6) owns tables [8w, 8w+8); lane&7 selects within.
    u32* tbl = s_acc[((tid >> 6) << 3) | (tid & 7)];

    for (int i = tid; i < NTBL * NUM_REGIONS; i += 256)
        (&s_acc[0][0])[i] = 0u;
    __syncthreads();

    const float4* real4 = (const float4*)real;
    const float4* fake4 = (const float4*)fake;
    const int4*   map4  = (const int4*)rmap;

    const int stride = gridDim.x * 256;
    for (int i = blockIdx.x * 256 + tid; i < n4; i += stride) {
        float4 a = real4[i];
        float4 b = fake4[i];
        int4   m = map4[i];
        u32 vx = (1u << CNT32_SHIFT) | (u32)(fabsf(a.x - b.x) * SUM_SCALE + 0.5f);
        u32 vy = (1u << CNT32_SHIFT) | (u32)(fabsf(a.y - b.y) * SUM_SCALE + 0.5f);
        u32 vz = (1u << CNT32_SHIFT) | (u32)(fabsf(a.z - b.z) * SUM_SCALE + 0.5f);
        u32 vw = (1u << CNT32_SHIFT) | (u32)(fabsf(a.w - b.w) * SUM_SCALE + 0.5f);
        atomicAdd(&tbl[m.x], vx);
        atomicAdd(&tbl[m.y], vy);
        atomicAdd(&tbl[m.z], vz);
        atomicAdd(&tbl[m.w], vw);
    }

    // Scalar tail (n not divisible by 4) — block 0.
    const int tail = n4 << 2;
    if (blockIdx.x == 0 && tid < (n - tail)) {
        int idx = tail + tid;
        u32 v = (1u << CNT32_SHIFT) |
                (u32)(fabsf(real[idx] - fake[idx]) * SUM_SCALE + 0.5f);
        atomicAdd(&tbl[rmap[idx]], v);
    }
    __syncthreads();

    // Merge 32 tables -> one u64 global atomic per region per block.
    for (int r = tid; r < NUM_REGIONS; r += 256) {
        u64 sum = 0, cnt = 0;
#pragma unroll
        for (int k = 0; k < NTBL; ++k) {
            u32 v = s_acc[k][r];
            sum += (u64)(v & SUM32_MASK);
            cnt += (u64)(v >> CNT32_SHIFT);
        }
        u64 packed = (cnt << CNT_SHIFT) | sum;
        if (packed) atomicAdd(&g_acc[r], packed);
    }
}

__global__ __launch_bounds__(64) void region_finalize_kernel(
    const u64* __restrict__ g_acc,
    float* __restrict__ out,
    float inv_n)
{
    const int lane = threadIdx.x;  // one wave
    u64 tA = g_acc[lane];
    float sA = (float)(tA & SUM_MASK) * FIX_INV;
    float cA = (float)(tA >> CNT_SHIFT);
    float mA = sA / (cA + EPS);

    float sB = 0.0f, mB = 0.0f;
    if (lane + 64 < NUM_REGIONS) {
        u64 tB = g_acc[lane + 64];
        sB = (float)(tB & SUM_MASK) * FIX_INV;
        float cB = (float)(tB >> CNT_SHIFT);
        mB = sB / (cB + EPS);
    }

    float mx = fmaxf(mA, mB);
#pragma unroll
    for (int off = 32; off > 0; off >>= 1)
        mx = fmaxf(mx, __shfl_xor(mx, off));
    mx = fmaxf(mx, 0.0f);  // jnp.maximum(max, 0.0)

    const float k = GAMMA / (mx + EPS);
    float part = sA * (1.0f + mA * k) + sB * (1.0f + mB * k);
#pragma unroll
    for (int off = 32; off > 0; off >>= 1)
        part += __shfl_xor(part, off);

    if (lane == 0)
        out[0] = part * inv_n;
}

extern "C" void kernel_launch(void* const* d_in, const int* in_sizes, int n_in,
                              void* d_out, int out_size, void* d_ws, size_t ws_size,
                              hipStream_t stream) {
    const float* real = (const float*)d_in[0];
    const float* fake = (const float*)d_in[1];
    const int*   rmap = (const int*)d_in[2];
    float* out = (float*)d_out;

    const int n  = in_sizes[0];
    const int n4 = n >> 2;

    u64* g_acc = (u64*)d_ws;
    hipMemsetAsync(d_ws, 0, NUM_REGIONS * sizeof(u64), stream);

    int blocks = (n4 + 255) / 256;
    if (blocks > 2048) blocks = 2048;
    if (blocks < 1) blocks = 1;

    region_accum_kernel<<<blocks, 256, 0, stream>>>(real, fake, rmap, g_acc, n, n4);
    region_finalize_kernel<<<1, 64, 0, stream>>>(g_acc, out, 1.0f / (float)n);
}